// Round 7
// baseline (926.769 us; speedup 1.0000x reference)
//
#include <hip/hip_runtime.h>
#include <math.h>

#define B_ 4
#define N_ 4096
#define C_ 64
#define K1_ 4
#define K2_ 6
#define EPS_ 1e-5f
#define BN_ (B_ * N_)
#define NCH_ 16
#define CHP_ 256
#define STKD_ 16

#define MODE_GATHER 0
#define MODE_PLAIN 2

typedef __attribute__((ext_vector_type(8))) short bf16x8;
typedef __attribute__((ext_vector_type(4))) float f32x4;
typedef __attribute__((ext_vector_type(2))) float f32x2;

__device__ __forceinline__ unsigned short f2bf(float f) {
  unsigned int u = __float_as_uint(f);
  unsigned int r = (u + 0x7fffu + ((u >> 16) & 1u)) >> 16;
  return (unsigned short)r;
}
__device__ __forceinline__ float bf2f(unsigned short u) {
  return __uint_as_float(((unsigned int)u) << 16);
}

// ---------------- pose + point-table build -------------------------------------
__global__ __launch_bounds__(256) void k_pose(const float* __restrict__ pos1,
                                              const float* __restrict__ pos2,
                                              const float* __restrict__ qc,
                                              const float* __restrict__ tc,
                                              float* __restrict__ posw,
                                              float4* __restrict__ pts4w,
                                              float4* __restrict__ pairW,
                                              float4* __restrict__ pairP) {
  int t = blockIdx.x * 256 + threadIdx.x;
  if (t >= BN_) return;
  int b = t / N_;
  float qw = qc[b * 4 + 0], qx = qc[b * 4 + 1], qy = qc[b * 4 + 2], qz = qc[b * 4 + 3];
  float vx = pos1[t * 3 + 0], vy = pos1[t * 3 + 1], vz = pos1[t * 3 + 2];
  float aw = -(qx * vx + qy * vy + qz * vz);
  float ax = qw * vx + qy * vz - qz * vy;
  float ay = qw * vy - qx * vz + qz * vx;
  float az = qw * vz + qx * vy - qy * vx;
  float n2 = qw * qw + qx * qx + qy * qy + qz * qz + 1e-10f;
  float bw = qw / n2, bx = -qx / n2, by = -qy / n2, bz = -qz / n2;
  float rx = aw * bx + ax * bw + ay * bz - az * by;
  float ry = aw * by - ax * bz + ay * bw + az * bx;
  float rz = aw * bz + ax * by - ay * bx + az * bw;
  rx += tc[b * 3 + 0];
  ry += tc[b * 3 + 1];
  rz += tc[b * 3 + 2];
  posw[t * 3 + 0] = rx;
  posw[t * 3 + 1] = ry;
  posw[t * 3 + 2] = rz;
  float rw2 = rx * rx + ry * ry + rz * rz;
  pts4w[t] = make_float4(rx, ry, rz, rw2);
  int p = t >> 1, h = t & 1;
  float* bwp = (float*)&pairW[(size_t)2 * p];
  bwp[0 + h] = rx; bwp[2 + h] = ry; bwp[4 + h] = rz; bwp[6 + h] = rw2;
  float px = pos2[t * 3 + 0], py = pos2[t * 3 + 1], pz = pos2[t * 3 + 2];
  float pw2 = px * px + py * py + pz * pz;
  float* bpp = (float*)&pairP[(size_t)2 * p];
  bpp[0 + h] = px; bpp[2 + h] = py; bpp[4 + h] = pz; bpp[6 + h] = pw2;
}

// ---------------- branchless bubble top-6 insert on packed int keys ------------
// Unique keys (j embedded) => total order; bubble maintains ascending kd[0..5].
// Bit-identical result to positional insert, ~half the VALU.
__device__ __forceinline__ void ins6i(int (&kd)[6], int k) {
  int x = k;
#pragma unroll
  for (int u = 0; u < 6; ++u) {
    int lo = min(kd[u], x);
    x = max(kd[u], x);
    kd[u] = lo;
  }
}

// ---------------- fused dual-KNN, packed keys + LDS candidate stacks -----------
__global__ __launch_bounds__(256) void k_knn2(const float4* __restrict__ pts4w,
                                              const float4* __restrict__ pairW,
                                              const float4* __restrict__ pairP,
                                              int* __restrict__ outK) {
  __shared__ int st[STKD_][256];
  int tid = threadIdx.x;
  int b = blockIdx.z & 3;
  int which = blockIdx.z >> 2;
  const f32x4* __restrict__ PT =
      (const f32x4*)((which ? pairW : pairP) + (size_t)b * N_ + blockIdx.y * CHP_);
  int base = blockIdx.y * CHP_;
  int n = blockIdx.x * 256 + tid;
  float4 qv = pts4w[(size_t)b * N_ + n];
  f32x2 qq2 = (f32x2)(qv.w);
  f32x2 m2x = (f32x2)(-2.f * qv.x);
  f32x2 m2y = (f32x2)(-2.f * qv.y);
  f32x2 m2z = (f32x2)(-2.f * qv.z);
  int kd[6];
#pragma unroll
  for (int t = 0; t < 6; ++t) kd[t] = 0x7fffffff;
  int kbd5 = 0x7fffffff;
  int ptr = 0;
  for (int jj = 0; jj < CHP_; jj += 4) {
    f32x4 e0 = PT[jj + 0];  // x0 x1 y0 y1
    f32x4 e1 = PT[jj + 1];  // z0 z1 w0 w1
    f32x4 e2 = PT[jj + 2];
    f32x4 e3 = PT[jj + 3];
    f32x2 d01 = __builtin_elementwise_fma(
        m2x, e0.xy,
        __builtin_elementwise_fma(m2y, e0.zw,
                                  __builtin_elementwise_fma(m2z, e1.xy, e1.zw + qq2)));
    f32x2 d23 = __builtin_elementwise_fma(
        m2x, e2.xy,
        __builtin_elementwise_fma(m2y, e2.zw,
                                  __builtin_elementwise_fma(m2z, e3.xy, e3.zw + qq2)));
    int j0 = base + jj;
    int k0 = (int)((__float_as_uint(d01.x) & 0xFFFFF000u) | (unsigned)(j0 + 0));
    int k1 = (int)((__float_as_uint(d01.y) & 0xFFFFF000u) | (unsigned)(j0 + 1));
    int k2 = (int)((__float_as_uint(d23.x) & 0xFFFFF000u) | (unsigned)(j0 + 2));
    int k3 = (int)((__float_as_uint(d23.y) & 0xFFFFF000u) | (unsigned)(j0 + 3));
    st[ptr][tid] = k0;
    ptr += (k0 < kbd5) ? 1 : 0;
    st[ptr][tid] = k1;
    ptr += (k1 < kbd5) ? 1 : 0;
    st[ptr][tid] = k2;
    ptr += (k2 < kbd5) ? 1 : 0;
    st[ptr][tid] = k3;
    ptr += (k3 < kbd5) ? 1 : 0;
    if (__ballot(ptr >= STKD_ - 4)) {
      for (int i = 0; i < ptr; ++i) ins6i(kd, st[i][tid]);
      ptr = 0;
      kbd5 = kd[5];
    }
  }
  for (int i = 0; i < ptr; ++i) ins6i(kd, st[i][tid]);
  size_t ob =
      ((size_t)which * BN_ * NCH_ + (size_t)(b * N_ + n) * NCH_ + blockIdx.y) * 6;
#pragma unroll
  for (int t = 0; t < 6; ++t) outK[ob + t] = kd[t];
}

__global__ __launch_bounds__(64) void k_knn2_merge(const int* __restrict__ inK,
                                                   int* __restrict__ idx2,
                                                   int* __restrict__ idx1) {
  int t = blockIdx.x * 64 + threadIdx.x;
  if (t >= 2 * BN_) return;
  int which = (t >= BN_) ? 1 : 0;
  int qi = t - which * BN_;
  int kd[6];
#pragma unroll
  for (int u = 0; u < 6; ++u) kd[u] = 0x7fffffff;
  size_t ib = ((size_t)which * BN_ + qi) * NCH_ * 6;
  for (int c = 0; c < NCH_ * 6; ++c) ins6i(kd, inK[ib + c]);
  if (which) {
#pragma unroll
    for (int u = 0; u < K1_; ++u) idx1[(size_t)qi * K1_ + u] = kd[u] & 0xFFF;
  } else {
#pragma unroll
    for (int u = 0; u < K2_; ++u) idx2[(size_t)qi * K2_ + u] = kd[u] & 0xFFF;
  }
}

// ---------------- weight pre-conversion to bf16 (padded, permuted) -------------
__global__ __launch_bounds__(256) void k_wconv_all(
    const float* __restrict__ W0, const float* __restrict__ W1,
    const float* __restrict__ W2, const float* __restrict__ W3,
    const float* __restrict__ W4, unsigned short* __restrict__ O0,
    unsigned short* __restrict__ O1, unsigned short* __restrict__ O2,
    unsigned short* __restrict__ O3, unsigned short* __restrict__ O4) {
  int m = blockIdx.y;
  const float* W;
  unsigned short* O;
  int COUT, CIN, KP, perm;
  switch (m) {
    case 0: W = W0; O = O0; COUT = 128; CIN = 131; KP = 160; perm = 1; break;
    case 1: W = W1; O = O1; COUT = 64; CIN = 128; KP = 128; perm = 0; break;
    case 2: W = W2; O = O2; COUT = 64; CIN = 64; KP = 64; perm = 0; break;
    case 3: W = W3; O = O3; COUT = 128; CIN = 131; KP = 160; perm = 1; break;
    default: W = W4; O = O4; COUT = 64; CIN = 128; KP = 128; perm = 0; break;
  }
  int t = blockIdx.x * 256 + threadIdx.x;
  if (t >= COUT * KP) return;
  int o = t / KP, k = t - o * KP;
  float v = 0.f;
  if (perm) {
    int c = (k < 128) ? (k + 3) : (k < 131) ? (k - 128) : -1;
    if (c >= 0) v = W[o * CIN + c];
  } else if (k < CIN) {
    v = W[o * CIN + k];
  }
  O[t] = f2bf(v);
}

// ---------------- fused gather/BN-relu + bf16-MFMA GEMM layer ------------------
// Row-split waves: wave wv owns rows [wv*16, wv*16+16) x ALL COUT columns.
// Per K-chunk per wave: 1 ds_read_b128 (A) feeds CT MFMAs; B preloaded in VGPRs
// (PRELB, COUT=64 layers) or streamed from L1/L2 (COUT=128 layers).
template <int CIN, int COUT, int KP, int MODE, int KNN, bool PRELB>
__global__ __launch_bounds__(256) void k_layer_mfma(
    const unsigned short* __restrict__ Wb,  // [COUT][KP] bf16
    const float* __restrict__ posP, const float* __restrict__ posQ,
    const float* __restrict__ featN, const float* __restrict__ feat1,
    const int* __restrict__ idx,
    const unsigned short* __restrict__ yprev,  // [rows][CIN] bf16 (PLAIN mode)
    const float* __restrict__ statPrev, const float* __restrict__ gPrev,
    const float* __restrict__ bPrev, float prevInvM,
    unsigned short* __restrict__ yout,  // [rows][COUT] bf16
    float* __restrict__ statOut) {
  constexpr int SP = KP + 8;    // ushort stride; SP*2 % 16 == 0 -> b128-aligned rows
  constexpr int CST = COUT + 8;
  constexpr int CT = COUT / 16;  // col tiles per wave (all columns)
  constexpr int NK = KP / 32;
  __shared__ unsigned short Xs[64 * SP];
  __shared__ float scl[CIN];
  __shared__ float shf[CIN];

  int tid = threadIdx.x;
  int row0 = blockIdx.x * 64;

  if (MODE == MODE_PLAIN) {
    for (int c = tid; c < CIN; c += 256) {
      float s = 0.f, s2 = 0.f;
#pragma unroll
      for (int u = 0; u < 8; ++u) {
        s += statPrev[c * 8 + u];
        s2 += statPrev[CIN * 8 + c * 8 + u];
      }
      float m = s * prevInvM;
      float v = s2 * prevInvM - m * m;
      float sc = gPrev[c] * rsqrtf(v + EPS_);
      scl[c] = sc;
      shf[c] = bPrev[c] - m * sc;
    }
    __syncthreads();
    constexpr int S4 = KP / 4;
    for (int e = tid; e < 64 * S4; e += 256) {
      int r = e / S4, s = e - r * S4;
      int row = row0 + r;
      ushort4 u = *(const ushort4*)&yprev[(size_t)row * CIN + s * 4];
      ushort4 o;
      o.x = f2bf(fmaxf(fmaf(bf2f(u.x), scl[s * 4 + 0], shf[s * 4 + 0]), 0.f));
      o.y = f2bf(fmaxf(fmaf(bf2f(u.y), scl[s * 4 + 1], shf[s * 4 + 1]), 0.f));
      o.z = f2bf(fmaxf(fmaf(bf2f(u.z), scl[s * 4 + 2], shf[s * 4 + 2]), 0.f));
      o.w = f2bf(fmaxf(fmaf(bf2f(u.w), scl[s * 4 + 3], shf[s * 4 + 3]), 0.f));
      *(ushort4*)&Xs[r * SP + s * 4] = o;
    }
  } else {
    // 4 threads per row; idx / batch / div computed ONCE per thread.
    int r = tid >> 2, sb = tid & 3;
    int row = row0 + r;
    int b = row / (N_ * KNN);
    int rem = row - b * (N_ * KNN);
    int n = rem / KNN;
    int j = idx[row];
    const float* fN = &featN[((size_t)(b * N_ + j)) * C_];
    const float* f1 = &feat1[((size_t)(b * N_ + n)) * C_];
#pragma unroll
    for (int s = sb; s < KP / 4; s += 4) {
      float4 v = make_float4(0.f, 0.f, 0.f, 0.f);
      if (s < 16) {
        v = *(const float4*)&fN[s * 4];
      } else if (s < 32) {
        v = *(const float4*)&f1[(s - 16) * 4];
      } else if (s == 32) {
        const float* pp = &posP[(size_t)(b * N_ + j) * 3];
        const float* pq = &posQ[(size_t)(b * N_ + n) * 3];
        v = make_float4(pp[0] - pq[0], pp[1] - pq[1], pp[2] - pq[2], 0.f);
      }
      ushort4 o;
      o.x = f2bf(v.x); o.y = f2bf(v.y); o.z = f2bf(v.z); o.w = f2bf(v.w);
      *(ushort4*)&Xs[r * SP + s * 4] = o;
    }
  }
  __syncthreads();

  int l = tid & 63, wv = tid >> 6;
  int lm = l & 15, quad = l >> 4;

  f32x4 acc[CT];
#pragma unroll
  for (int ct = 0; ct < CT; ++ct) acc[ct] = (f32x4)(0.f);

  const unsigned short* wbase = &Wb[(size_t)lm * KP + quad * 8];
  const unsigned short* arow = &Xs[(wv * 16 + lm) * SP + quad * 8];

  if constexpr (PRELB) {
    bf16x8 Breg[NK][CT];
#pragma unroll
    for (int kk = 0; kk < NK; ++kk)
#pragma unroll
      for (int ct = 0; ct < CT; ++ct)
        Breg[kk][ct] = *(const bf16x8*)&wbase[(size_t)ct * 16 * KP + kk * 32];
#pragma unroll
    for (int kk = 0; kk < NK; ++kk) {
      bf16x8 a = *(const bf16x8*)&arow[kk * 32];
#pragma unroll
      for (int ct = 0; ct < CT; ++ct)
        acc[ct] = __builtin_amdgcn_mfma_f32_16x16x32_bf16(a, Breg[kk][ct], acc[ct], 0, 0, 0);
    }
  } else {
#pragma unroll
    for (int kk = 0; kk < NK; ++kk) {
      bf16x8 a = *(const bf16x8*)&arow[kk * 32];
#pragma unroll
      for (int ct = 0; ct < CT; ++ct) {
        bf16x8 b = *(const bf16x8*)&wbase[(size_t)ct * 16 * KP + kk * 32];
        acc[ct] = __builtin_amdgcn_mfma_f32_16x16x32_bf16(a, b, acc[ct], 0, 0, 0);
      }
    }
  }

  // BN stats: reduce lane's 4 rows, then across quads (wave's 16 rows)
  int slot = blockIdx.x & 7;
#pragma unroll
  for (int ct = 0; ct < CT; ++ct) {
    float s1 = 0.f, s2 = 0.f;
#pragma unroll
    for (int r = 0; r < 4; ++r) {
      float v = acc[ct][r];
      s1 += v;
      s2 += v * v;
    }
    s1 += __shfl_xor(s1, 16);
    s1 += __shfl_xor(s1, 32);
    s2 += __shfl_xor(s2, 16);
    s2 += __shfl_xor(s2, 32);
    if (quad == 0) {
      int col = ct * 16 + lm;
      atomicAdd(&statOut[col * 8 + slot], s1);
      atomicAdd(&statOut[COUT * 8 + col * 8 + slot], s2);
    }
  }

  // restage D through LDS (bf16) for 16B-coalesced global stores
  __syncthreads();
  unsigned short* Ys = Xs;
#pragma unroll
  for (int ct = 0; ct < CT; ++ct)
#pragma unroll
    for (int r = 0; r < 4; ++r)
      Ys[(wv * 16 + quad * 4 + r) * CST + ct * 16 + lm] = f2bf(acc[ct][r]);
  __syncthreads();
  constexpr int S8 = COUT / 8;
  for (int e = tid; e < 64 * S8; e += 256) {
    int r = e / S8, c0 = (e - r * S8) * 8;
    uint4 v = *(const uint4*)&Ys[r * CST + c0];
    *(uint4*)&yout[((size_t)(row0 + r)) * COUT + c0] = v;
  }
}

// ---------------- fe = sum_k relu(bn(y3)), fp32 out ----------------------------
__global__ __launch_bounds__(256) void k_fe(const unsigned short* __restrict__ y3,
                                            const float* __restrict__ stat,
                                            const float* __restrict__ g,
                                            const float* __restrict__ bb,
                                            float* __restrict__ fe) {
  __shared__ float scl[C_], shf[C_];
  if (threadIdx.x < C_) {
    int c = threadIdx.x;
    float s = 0.f, s2 = 0.f;
#pragma unroll
    for (int u = 0; u < 8; ++u) {
      s += stat[c * 8 + u];
      s2 += stat[C_ * 8 + c * 8 + u];
    }
    const float invM = 1.f / (float)(BN_ * K2_);
    float m = s * invM;
    float v = s2 * invM - m * m;
    float sc = g[c] * rsqrtf(v + EPS_);
    scl[c] = sc;
    shf[c] = bb[c] - m * sc;
  }
  __syncthreads();
  int t = blockIdx.x * 256 + threadIdx.x;
  int bn = t >> 6, c = t & 63;
  float s = 0.f;
#pragma unroll
  for (int k = 0; k < K2_; ++k)
    s += fmaxf(fmaf(bf2f(y3[(size_t)(bn * K2_ + k) * C_ + c]), scl[c], shf[c]), 0.f);
  fe[t] = s;
}

// ---------------- pooled[b][c] = sum_{n,k} relu(bn(y5)) ------------------------
__global__ __launch_bounds__(256) void k_pooled(const unsigned short* __restrict__ y5,
                                                const float* __restrict__ stat,
                                                const float* __restrict__ g,
                                                const float* __restrict__ bb,
                                                float* __restrict__ pooled) {
  __shared__ float scl[C_], shf[C_];
  __shared__ float red[4][C_];
  if (threadIdx.x < C_) {
    int c = threadIdx.x;
    float s = 0.f, s2 = 0.f;
#pragma unroll
    for (int u = 0; u < 8; ++u) {
      s += stat[c * 8 + u];
      s2 += stat[C_ * 8 + c * 8 + u];
    }
    const float invM = 1.f / (float)(BN_ * K1_);
    float m = s * invM;
    float v = s2 * invM - m * m;
    float sc = g[c] * rsqrtf(v + EPS_);
    scl[c] = sc;
    shf[c] = bb[c] - m * sc;
  }
  __syncthreads();
  int c = threadIdx.x & 63;
  int rs = threadIdx.x >> 6;
  int row0 = blockIdx.x * 64;
  int b = row0 / (N_ * K1_);
  float s = 0.f;
  for (int i = 0; i < 16; ++i) {
    int row = row0 + rs * 16 + i;
    s += fmaxf(fmaf(bf2f(y5[(size_t)row * C_ + c]), scl[c], shf[c]), 0.f);
  }
  red[rs][c] = s;
  __syncthreads();
  if (threadIdx.x < C_) {
    float t2 = red[0][c] + red[1][c] + red[2][c] + red[3][c];
    atomicAdd(&pooled[(b * C_ + c) * 8 + (blockIdx.x & 7)], t2);
  }
}

// ---------------- head ---------------------------------------------------------
__global__ void k_final(const float* __restrict__ pooled, const float* __restrict__ wq,
                        const float* __restrict__ bq, const float* __restrict__ wt,
                        const float* __restrict__ bt, const float* __restrict__ qc,
                        const float* __restrict__ tc, float* __restrict__ out) {
  int b = threadIdx.x;
  if (b >= B_) return;
  float P[C_];
#pragma unroll
  for (int c = 0; c < C_; ++c) {
    float s = 0.f;
#pragma unroll
    for (int u = 0; u < 8; ++u) s += pooled[(b * C_ + c) * 8 + u];
    P[c] = s;
  }
  float qd[4];
#pragma unroll
  for (int i = 0; i < 4; ++i) {
    float s = bq[i];
#pragma unroll
    for (int c = 0; c < C_; ++c) s = fmaf(P[c], wq[i * C_ + c], s);
    qd[i] = s;
  }
  float td[3];
#pragma unroll
  for (int i = 0; i < 3; ++i) {
    float s = bt[i];
#pragma unroll
    for (int c = 0; c < C_; ++c) s = fmaf(P[c], wt[i * C_ + c], s);
    td[i] = s;
  }
  float nq = sqrtf(qd[0] * qd[0] + qd[1] * qd[1] + qd[2] * qd[2] + qd[3] * qd[3]) + 1e-10f;
#pragma unroll
  for (int i = 0; i < 4; ++i) qd[i] /= nq;
  float cw = qc[b * 4 + 0], cx = qc[b * 4 + 1], cyy = qc[b * 4 + 2], cz = qc[b * 4 + 3];
  float qnw = qd[0] * cw - qd[1] * cx - qd[2] * cyy - qd[3] * cz;
  float qnx = qd[0] * cx + qd[1] * cw + qd[2] * cz - qd[3] * cyy;
  float qny = qd[0] * cyy - qd[1] * cz + qd[2] * cw + qd[3] * cx;
  float qnz = qd[0] * cz + qd[1] * cyy - qd[2] * cx + qd[3] * cw;
  float nn = sqrtf(qnw * qnw + qnx * qnx + qny * qny + qnz * qnz) + 1e-10f;
  float vx = tc[b * 3 + 0], vy = tc[b * 3 + 1], vz = tc[b * 3 + 2];
  float aw = -(qd[1] * vx + qd[2] * vy + qd[3] * vz);
  float ax = qd[0] * vx + qd[2] * vz - qd[3] * vy;
  float ay = qd[0] * vy - qd[1] * vz + qd[3] * vx;
  float az = qd[0] * vz + qd[1] * vy - qd[2] * vx;
  float n2 = qd[0] * qd[0] + qd[1] * qd[1] + qd[2] * qd[2] + qd[3] * qd[3] + 1e-10f;
  float bw = qd[0] / n2, bx = -qd[1] / n2, by = -qd[2] / n2, bz = -qd[3] / n2;
  float rx = aw * bx + ax * bw + ay * bz - az * by;
  float ry = aw * by - ax * bz + ay * bw + az * bx;
  float rz = aw * bz + ax * by - ay * bx + az * bw;
  out[b * 7 + 0] = qnw / nn;
  out[b * 7 + 1] = qnx / nn;
  out[b * 7 + 2] = qny / nn;
  out[b * 7 + 3] = qnz / nn;
  out[b * 7 + 4] = rx + td[0];
  out[b * 7 + 5] = ry + td[1];
  out[b * 7 + 6] = rz + td[2];
}

extern "C" void kernel_launch(void* const* d_in, const int* in_sizes, int n_in,
                              void* d_out, int out_size, void* d_ws, size_t ws_size,
                              hipStream_t stream) {
  const float* pos1 = (const float*)d_in[0];
  const float* pos2 = (const float*)d_in[1];
  const float* feat1 = (const float*)d_in[2];
  const float* feat2 = (const float*)d_in[3];
  const float* qc = (const float*)d_in[4];
  const float* tc = (const float*)d_in[5];
  const float* w1_0 = (const float*)d_in[6];
  const float* g1_0 = (const float*)d_in[7];
  const float* b1_0 = (const float*)d_in[8];
  const float* w1_1 = (const float*)d_in[9];
  const float* g1_1 = (const float*)d_in[10];
  const float* b1_1 = (const float*)d_in[11];
  const float* w1_2 = (const float*)d_in[12];
  const float* g1_2 = (const float*)d_in[13];
  const float* b1_2 = (const float*)d_in[14];
  const float* w2_0 = (const float*)d_in[15];
  const float* g2_0 = (const float*)d_in[16];
  const float* b2_0 = (const float*)d_in[17];
  const float* w2_1 = (const float*)d_in[18];
  const float* g2_1 = (const float*)d_in[19];
  const float* b2_1 = (const float*)d_in[20];
  const float* wq = (const float*)d_in[21];
  const float* bq = (const float*)d_in[22];
  const float* wt = (const float*)d_in[23];
  const float* bt = (const float*)d_in[24];

  float* ws = (float*)d_ws;
  const size_t off_posw = 0;                  // 49152
  const size_t off_fe = 49152;                // 1048576 (fp32)
  const size_t off_stat = 1097728;            // 8192
  const size_t off_pool = 1105920;            // 2048
  const size_t off_idx2 = 1107968;            // 98304 (int)
  const size_t off_idx1 = 1206272;            // 65536 (int)
  const size_t off_wb = 1271808;              // 30720 floats = 61440 bf16
  const size_t off_pts4w = 1302528;           // 65536 (float4 x 16384)
  const size_t off_pairW = 1368064;           // 65536
  const size_t off_pairP = 1433600;           // 65536
  const size_t off_yA = 1499136;              // 6291456 floats = 12582912 bf16
  const size_t off_yB = 7790592;              // 3145728 floats = 6291456 bf16

  float* posw = ws + off_posw;
  float* fe = ws + off_fe;
  float* stat0 = ws + off_stat;  // 128*16
  float* stat1 = stat0 + 2048;   // 64*16
  float* stat2 = stat1 + 1024;   // 64*16
  float* stat3 = stat2 + 1024;   // 128*16
  float* stat4 = stat3 + 2048;   // 64*16
  float* pooled = ws + off_pool;
  int* idx2 = (int*)(ws + off_idx2);
  int* idx1 = (int*)(ws + off_idx1);
  unsigned short* wb0 = (unsigned short*)(ws + off_wb);  // 128x160
  unsigned short* wb1 = wb0 + 20480;                     // 64x128
  unsigned short* wb2 = wb1 + 8192;                      // 64x64
  unsigned short* wb3 = wb2 + 4096;                      // 128x160
  unsigned short* wb4 = wb3 + 20480;                     // 64x128
  float4* pts4w = (float4*)(ws + off_pts4w);
  float4* pairW = (float4*)(ws + off_pairW);
  float4* pairP = (float4*)(ws + off_pairP);
  unsigned short* yA = (unsigned short*)(ws + off_yA);
  unsigned short* yB = (unsigned short*)(ws + off_yB);
  // KNN partial-key scratch overlaps yA (used strictly before the layer kernels)
  int* knnK = (int*)yA;

  hipMemsetAsync(ws + off_stat, 0, (8192 + 2048) * sizeof(float), stream);

  k_wconv_all<<<dim3(80, 5), 256, 0, stream>>>(w1_0, w1_1, w1_2, w2_0, w2_1, wb0, wb1,
                                               wb2, wb3, wb4);
  k_pose<<<dim3(BN_ / 256), 256, 0, stream>>>(pos1, pos2, qc, tc, posw, pts4w, pairW,
                                              pairP);

  // fused dual KNN: grid (16 query-blocks, 16 chunks, 4 batches x 2 KNNs)
  k_knn2<<<dim3(N_ / 256, NCH_, 2 * B_), 256, 0, stream>>>(pts4w, pairW, pairP, knnK);
  k_knn2_merge<<<dim3(2 * BN_ / 64), 64, 0, stream>>>(knnK, idx2, idx1);

  // MLP1 L0: gather(pos2,feat2)+feat1 -> 128ch, y into yA
  k_layer_mfma<131, 128, 160, MODE_GATHER, K2_, false>
      <<<dim3(98304 / 64), 256, 0, stream>>>(wb0, pos2, posw, feat2, feat1, idx2,
                                             nullptr, nullptr, nullptr, nullptr, 0.f,
                                             yA, stat0);
  // MLP1 L1: 128->64, yA -> yB
  k_layer_mfma<128, 64, 128, MODE_PLAIN, 1, true>
      <<<dim3(98304 / 64), 256, 0, stream>>>(wb1, nullptr, nullptr, nullptr, nullptr,
                                             nullptr, yA, stat0, g1_0, b1_0,
                                             1.f / 98304.f, yB, stat1);
  // MLP1 L2: 64->64, yB -> yA
  k_layer_mfma<64, 64, 64, MODE_PLAIN, 1, true>
      <<<dim3(98304 / 64), 256, 0, stream>>>(wb2, nullptr, nullptr, nullptr, nullptr,
                                             nullptr, yB, stat1, g1_1, b1_1,
                                             1.f / 98304.f, yA, stat2);
  // fe = sum_k relu(bn(yA))
  k_fe<<<dim3(BN_ * C_ / 256), 256, 0, stream>>>(yA, stat2, g1_2, b1_2, fe);
  // MLP2 L0: gather(posw, fe)+feat1 -> 128ch, into yA
  k_layer_mfma<131, 128, 160, MODE_GATHER, K1_, false>
      <<<dim3(65536 / 64), 256, 0, stream>>>(wb3, posw, posw, fe, feat1, idx1, nullptr,
                                             nullptr, nullptr, nullptr, 0.f, yA, stat3);
  // MLP2 L1: 128->64, yA -> yB
  k_layer_mfma<128, 64, 128, MODE_PLAIN, 1, true>
      <<<dim3(65536 / 64), 256, 0, stream>>>(wb4, nullptr, nullptr, nullptr, nullptr,
                                             nullptr, yA, stat3, g2_0, b2_0,
                                             1.f / 65536.f, yB, stat4);
  // pooled
  k_pooled<<<dim3(65536 / 64), 256, 0, stream>>>(yB, stat4, g2_1, b2_1, pooled);
  // head
  k_final<<<dim3(1), 64, 0, stream>>>(pooled, wq, bq, wt, bt, qc, tc, (float*)d_out);
}

// Round 8
// 488.151 us; speedup vs baseline: 1.8985x; 1.8985x over previous
//
#include <hip/hip_runtime.h>
#include <math.h>

#define B_ 4
#define N_ 4096
#define C_ 64
#define K1_ 4
#define K2_ 6
#define EPS_ 1e-5f
#define BN_ (B_ * N_)
#define NCH_ 16
#define CHP_ 256
#define STKD_ 16

#define MODE_GATHER 0
#define MODE_PLAIN 2

typedef __attribute__((ext_vector_type(8))) short bf16x8;
typedef __attribute__((ext_vector_type(4))) float f32x4;
typedef __attribute__((ext_vector_type(2))) float f32x2;

__device__ __forceinline__ unsigned short f2bf(float f) {
  unsigned int u = __float_as_uint(f);
  unsigned int r = (u + 0x7fffu + ((u >> 16) & 1u)) >> 16;
  return (unsigned short)r;
}
__device__ __forceinline__ float bf2f(unsigned short u) {
  return __uint_as_float(((unsigned int)u) << 16);
}

// ---------------- pose + point-table build -------------------------------------
__global__ __launch_bounds__(256) void k_pose(const float* __restrict__ pos1,
                                              const float* __restrict__ pos2,
                                              const float* __restrict__ qc,
                                              const float* __restrict__ tc,
                                              float* __restrict__ posw,
                                              float4* __restrict__ pts4w,
                                              float4* __restrict__ pairW,
                                              float4* __restrict__ pairP) {
  int t = blockIdx.x * 256 + threadIdx.x;
  if (t >= BN_) return;
  int b = t / N_;
  float qw = qc[b * 4 + 0], qx = qc[b * 4 + 1], qy = qc[b * 4 + 2], qz = qc[b * 4 + 3];
  float vx = pos1[t * 3 + 0], vy = pos1[t * 3 + 1], vz = pos1[t * 3 + 2];
  float aw = -(qx * vx + qy * vy + qz * vz);
  float ax = qw * vx + qy * vz - qz * vy;
  float ay = qw * vy - qx * vz + qz * vx;
  float az = qw * vz + qx * vy - qy * vx;
  float n2 = qw * qw + qx * qx + qy * qy + qz * qz + 1e-10f;
  float bw = qw / n2, bx = -qx / n2, by = -qy / n2, bz = -qz / n2;
  float rx = aw * bx + ax * bw + ay * bz - az * by;
  float ry = aw * by - ax * bz + ay * bw + az * bx;
  float rz = aw * bz + ax * by - ay * bx + az * bw;
  rx += tc[b * 3 + 0];
  ry += tc[b * 3 + 1];
  rz += tc[b * 3 + 2];
  posw[t * 3 + 0] = rx;
  posw[t * 3 + 1] = ry;
  posw[t * 3 + 2] = rz;
  float rw2 = rx * rx + ry * ry + rz * rz;
  pts4w[t] = make_float4(rx, ry, rz, rw2);
  int p = t >> 1, h = t & 1;
  float* bwp = (float*)&pairW[(size_t)2 * p];
  bwp[0 + h] = rx; bwp[2 + h] = ry; bwp[4 + h] = rz; bwp[6 + h] = rw2;
  float px = pos2[t * 3 + 0], py = pos2[t * 3 + 1], pz = pos2[t * 3 + 2];
  float pw2 = px * px + py * py + pz * pz;
  float* bpp = (float*)&pairP[(size_t)2 * p];
  bpp[0 + h] = px; bpp[2 + h] = py; bpp[4 + h] = pz; bpp[6 + h] = pw2;
}

// ---------------- branchless bubble top-6 insert on packed int keys ------------
__device__ __forceinline__ void ins6i(int (&kd)[6], int k) {
  int x = k;
#pragma unroll
  for (int u = 0; u < 6; ++u) {
    int lo = min(kd[u], x);
    x = max(kd[u], x);
    kd[u] = lo;
  }
}

// ---------------- fused dual-KNN, packed keys + LDS candidate stacks -----------
__global__ __launch_bounds__(256) void k_knn2(const float4* __restrict__ pts4w,
                                              const float4* __restrict__ pairW,
                                              const float4* __restrict__ pairP,
                                              int* __restrict__ outK) {
  __shared__ int st[STKD_][256];
  int tid = threadIdx.x;
  int b = blockIdx.z & 3;
  int which = blockIdx.z >> 2;
  const f32x4* __restrict__ PT =
      (const f32x4*)((which ? pairW : pairP) + (size_t)b * N_ + blockIdx.y * CHP_);
  int base = blockIdx.y * CHP_;
  int n = blockIdx.x * 256 + tid;
  float4 qv = pts4w[(size_t)b * N_ + n];
  f32x2 qq2 = (f32x2)(qv.w);
  f32x2 m2x = (f32x2)(-2.f * qv.x);
  f32x2 m2y = (f32x2)(-2.f * qv.y);
  f32x2 m2z = (f32x2)(-2.f * qv.z);
  int kd[6];
#pragma unroll
  for (int t = 0; t < 6; ++t) kd[t] = 0x7fffffff;
  int kbd5 = 0x7fffffff;
  int ptr = 0;
  for (int jj = 0; jj < CHP_; jj += 4) {
    f32x4 e0 = PT[jj + 0];
    f32x4 e1 = PT[jj + 1];
    f32x4 e2 = PT[jj + 2];
    f32x4 e3 = PT[jj + 3];
    f32x2 d01 = __builtin_elementwise_fma(
        m2x, e0.xy,
        __builtin_elementwise_fma(m2y, e0.zw,
                                  __builtin_elementwise_fma(m2z, e1.xy, e1.zw + qq2)));
    f32x2 d23 = __builtin_elementwise_fma(
        m2x, e2.xy,
        __builtin_elementwise_fma(m2y, e2.zw,
                                  __builtin_elementwise_fma(m2z, e3.xy, e3.zw + qq2)));
    int j0 = base + jj;
    int k0 = (int)((__float_as_uint(d01.x) & 0xFFFFF000u) | (unsigned)(j0 + 0));
    int k1 = (int)((__float_as_uint(d01.y) & 0xFFFFF000u) | (unsigned)(j0 + 1));
    int k2 = (int)((__float_as_uint(d23.x) & 0xFFFFF000u) | (unsigned)(j0 + 2));
    int k3 = (int)((__float_as_uint(d23.y) & 0xFFFFF000u) | (unsigned)(j0 + 3));
    st[ptr][tid] = k0;
    ptr += (k0 < kbd5) ? 1 : 0;
    st[ptr][tid] = k1;
    ptr += (k1 < kbd5) ? 1 : 0;
    st[ptr][tid] = k2;
    ptr += (k2 < kbd5) ? 1 : 0;
    st[ptr][tid] = k3;
    ptr += (k3 < kbd5) ? 1 : 0;
    if (__ballot(ptr >= STKD_ - 4)) {
      for (int i = 0; i < ptr; ++i) ins6i(kd, st[i][tid]);
      ptr = 0;
      kbd5 = kd[5];
    }
  }
  for (int i = 0; i < ptr; ++i) ins6i(kd, st[i][tid]);
  size_t ob =
      ((size_t)which * BN_ * NCH_ + (size_t)(b * N_ + n) * NCH_ + blockIdx.y) * 6;
#pragma unroll
  for (int t = 0; t < 6; ++t) outK[ob + t] = kd[t];
}

__global__ __launch_bounds__(64) void k_knn2_merge(const int* __restrict__ inK,
                                                   int* __restrict__ idx2,
                                                   int* __restrict__ idx1) {
  int t = blockIdx.x * 64 + threadIdx.x;
  if (t >= 2 * BN_) return;
  int which = (t >= BN_) ? 1 : 0;
  int qi = t - which * BN_;
  int kd[6];
#pragma unroll
  for (int u = 0; u < 6; ++u) kd[u] = 0x7fffffff;
  size_t ib = ((size_t)which * BN_ + qi) * NCH_ * 6;
  for (int c = 0; c < NCH_ * 6; ++c) ins6i(kd, inK[ib + c]);
  if (which) {
#pragma unroll
    for (int u = 0; u < K1_; ++u) idx1[(size_t)qi * K1_ + u] = kd[u] & 0xFFF;
  } else {
#pragma unroll
    for (int u = 0; u < K2_; ++u) idx2[(size_t)qi * K2_ + u] = kd[u] & 0xFFF;
  }
}

// ---------------- weight pre-conversion to bf16 (padded, permuted) -------------
__global__ __launch_bounds__(256) void k_wconv_all(
    const float* __restrict__ W0, const float* __restrict__ W1,
    const float* __restrict__ W2, const float* __restrict__ W3,
    const float* __restrict__ W4, unsigned short* __restrict__ O0,
    unsigned short* __restrict__ O1, unsigned short* __restrict__ O2,
    unsigned short* __restrict__ O3, unsigned short* __restrict__ O4) {
  int m = blockIdx.y;
  const float* W;
  unsigned short* O;
  int COUT, CIN, KP, perm;
  switch (m) {
    case 0: W = W0; O = O0; COUT = 128; CIN = 131; KP = 160; perm = 1; break;
    case 1: W = W1; O = O1; COUT = 64; CIN = 128; KP = 128; perm = 0; break;
    case 2: W = W2; O = O2; COUT = 64; CIN = 64; KP = 64; perm = 0; break;
    case 3: W = W3; O = O3; COUT = 128; CIN = 131; KP = 160; perm = 1; break;
    default: W = W4; O = O4; COUT = 64; CIN = 128; KP = 128; perm = 0; break;
  }
  int t = blockIdx.x * 256 + threadIdx.x;
  if (t >= COUT * KP) return;
  int o = t / KP, k = t - o * KP;
  float v = 0.f;
  if (perm) {
    int c = (k < 128) ? (k + 3) : (k < 131) ? (k - 128) : -1;
    if (c >= 0) v = W[o * CIN + c];
  } else if (k < CIN) {
    v = W[o * CIN + k];
  }
  O[t] = f2bf(v);
}

// ---------------- fused gather/BN-relu + bf16-MFMA GEMM layer ------------------
// Round-6 column-split structure. Stats: per-block coalesced partial store
// (NO global atomics — atomic coherence traffic was the R7 bottleneck).
template <int CIN, int COUT, int KP, int MODE, int KNN>
__global__ __launch_bounds__(256) void k_layer_mfma(
    const unsigned short* __restrict__ Wb,  // [COUT][KP] bf16
    const float* __restrict__ posP, const float* __restrict__ posQ,
    const float* __restrict__ featN, const float* __restrict__ feat1,
    const int* __restrict__ idx,
    const unsigned short* __restrict__ yprev,  // [rows][CIN] bf16 (PLAIN mode)
    const float* __restrict__ statPrev, const float* __restrict__ gPrev,
    const float* __restrict__ bPrev, float prevInvM,
    unsigned short* __restrict__ yout,  // [rows][COUT] bf16
    float* __restrict__ partialOut) {   // [grid][2*COUT] block sums
  constexpr int SP = KP + 8;
  constexpr int CST = COUT + 8;
  constexpr int CT = COUT / 64;
  __shared__ unsigned short Xs[64 * SP];
  __shared__ float scl[CIN];
  __shared__ float shf[CIN];

  int tid = threadIdx.x;
  int row0 = blockIdx.x * 64;

  if (MODE == MODE_PLAIN) {
    for (int c = tid; c < CIN; c += 256) {
      float s = 0.f, s2 = 0.f;
#pragma unroll
      for (int u = 0; u < 8; ++u) {
        s += statPrev[c * 8 + u];
        s2 += statPrev[CIN * 8 + c * 8 + u];
      }
      float m = s * prevInvM;
      float v = s2 * prevInvM - m * m;
      float sc = gPrev[c] * rsqrtf(v + EPS_);
      scl[c] = sc;
      shf[c] = bPrev[c] - m * sc;
    }
    __syncthreads();
    constexpr int S4 = KP / 4;
    for (int e = tid; e < 64 * S4; e += 256) {
      int r = e / S4, s = e - r * S4;
      int row = row0 + r;
      ushort4 u = *(const ushort4*)&yprev[(size_t)row * CIN + s * 4];
      ushort4 o;
      o.x = f2bf(fmaxf(fmaf(bf2f(u.x), scl[s * 4 + 0], shf[s * 4 + 0]), 0.f));
      o.y = f2bf(fmaxf(fmaf(bf2f(u.y), scl[s * 4 + 1], shf[s * 4 + 1]), 0.f));
      o.z = f2bf(fmaxf(fmaf(bf2f(u.z), scl[s * 4 + 2], shf[s * 4 + 2]), 0.f));
      o.w = f2bf(fmaxf(fmaf(bf2f(u.w), scl[s * 4 + 3], shf[s * 4 + 3]), 0.f));
      *(ushort4*)&Xs[r * SP + s * 4] = o;
    }
  } else {
    constexpr int S4 = KP / 4;
    for (int e = tid; e < 64 * S4; e += 256) {
      int r = e / S4, s = e - r * S4;
      int row = row0 + r;
      int b = row / (N_ * KNN);
      int rem = row - b * (N_ * KNN);
      int n = rem / KNN;
      float4 v = make_float4(0.f, 0.f, 0.f, 0.f);
      if (s < 16) {
        int j = idx[row];
        v = *(const float4*)&featN[((size_t)(b * N_ + j)) * C_ + s * 4];
      } else if (s < 32) {
        v = *(const float4*)&feat1[((size_t)(b * N_ + n)) * C_ + (s - 16) * 4];
      } else if (s == 32) {
        int j = idx[row];
        const float* pp = &posP[(size_t)(b * N_ + j) * 3];
        const float* pq = &posQ[(size_t)(b * N_ + n) * 3];
        v = make_float4(pp[0] - pq[0], pp[1] - pq[1], pp[2] - pq[2], 0.f);
      }
      ushort4 o;
      o.x = f2bf(v.x); o.y = f2bf(v.y); o.z = f2bf(v.z); o.w = f2bf(v.w);
      *(ushort4*)&Xs[r * SP + s * 4] = o;
    }
  }
  __syncthreads();

  int l = tid & 63, wv = tid >> 6;
  int lm = l & 15, quad = l >> 4;
  int n0 = wv * (COUT / 4);

  f32x4 acc[4][CT];
#pragma unroll
  for (int rt = 0; rt < 4; ++rt)
#pragma unroll
    for (int ct = 0; ct < CT; ++ct) acc[rt][ct] = (f32x4)(0.f);

#pragma unroll
  for (int k0 = 0; k0 < KP; k0 += 32) {
    bf16x8 a[4], b[CT];
#pragma unroll
    for (int rt = 0; rt < 4; ++rt)
      a[rt] = *(const bf16x8*)&Xs[(rt * 16 + lm) * SP + k0 + quad * 8];
#pragma unroll
    for (int ct = 0; ct < CT; ++ct)
      b[ct] = *(const bf16x8*)&Wb[(size_t)(n0 + ct * 16 + lm) * KP + k0 + quad * 8];
#pragma unroll
    for (int rt = 0; rt < 4; ++rt)
#pragma unroll
      for (int ct = 0; ct < CT; ++ct)
        acc[rt][ct] =
            __builtin_amdgcn_mfma_f32_16x16x32_bf16(a[rt], b[ct], acc[rt][ct], 0, 0, 0);
  }

  // BN stats: reduce lane's 16 rows + cross-quad shuffle -> per-col block sums,
  // stored as ONE coalesced partial vector per block (no atomics).
  float* pbase = &partialOut[(size_t)blockIdx.x * 2 * COUT];
#pragma unroll
  for (int ct = 0; ct < CT; ++ct) {
    float s1 = 0.f, s2 = 0.f;
#pragma unroll
    for (int rt = 0; rt < 4; ++rt)
#pragma unroll
      for (int r = 0; r < 4; ++r) {
        float v = acc[rt][ct][r];
        s1 += v;
        s2 += v * v;
      }
    s1 += __shfl_xor(s1, 16);
    s1 += __shfl_xor(s1, 32);
    s2 += __shfl_xor(s2, 16);
    s2 += __shfl_xor(s2, 32);
    if (quad == 0) {
      int col = n0 + ct * 16 + lm;
      pbase[col] = s1;
      pbase[COUT + col] = s2;
    }
  }

  __syncthreads();
  unsigned short* Ys = Xs;
#pragma unroll
  for (int rt = 0; rt < 4; ++rt)
#pragma unroll
    for (int ct = 0; ct < CT; ++ct)
#pragma unroll
      for (int r = 0; r < 4; ++r)
        Ys[(rt * 16 + quad * 4 + r) * CST + n0 + ct * 16 + lm] = f2bf(acc[rt][ct][r]);
  __syncthreads();
  constexpr int S8 = COUT / 8;
  for (int e = tid; e < 64 * S8; e += 256) {
    int r = e / S8, c0 = (e - r * S8) * 8;
    uint4 v = *(const uint4*)&Ys[r * CST + c0];
    *(uint4*)&yout[((size_t)(row0 + r)) * COUT + c0] = v;
  }
}

// ---------------- partial -> 8-slot stat reduction (no atomics) ----------------
// grid 8 x 256. Block i sums partial[g][t] over its G/8 stripe, coalesced in t.
// Output layout matches consumers: stat[s*COUT*8 + c*8 + i].
template <int COUT>
__global__ __launch_bounds__(256) void k_statreduce(const float* __restrict__ partial,
                                                    int G, float* __restrict__ statOut) {
  int i = blockIdx.x;
  int t = threadIdx.x;
  if (t >= 2 * COUT) return;
  int gs = G >> 3;
  int g0 = i * gs, g1 = g0 + gs;
  float s = 0.f;
  for (int g = g0; g < g1; ++g) s += partial[(size_t)g * 2 * COUT + t];
  int sIdx = t / COUT, c = t - sIdx * COUT;
  statOut[sIdx * COUT * 8 + c * 8 + i] = s;
}

// ---------------- fe = sum_k relu(bn(y3)), fp32 out ----------------------------
__global__ __launch_bounds__(256) void k_fe(const unsigned short* __restrict__ y3,
                                            const float* __restrict__ stat,
                                            const float* __restrict__ g,
                                            const float* __restrict__ bb,
                                            float* __restrict__ fe) {
  __shared__ float scl[C_], shf[C_];
  if (threadIdx.x < C_) {
    int c = threadIdx.x;
    float s = 0.f, s2 = 0.f;
#pragma unroll
    for (int u = 0; u < 8; ++u) {
      s += stat[c * 8 + u];
      s2 += stat[C_ * 8 + c * 8 + u];
    }
    const float invM = 1.f / (float)(BN_ * K2_);
    float m = s * invM;
    float v = s2 * invM - m * m;
    float sc = g[c] * rsqrtf(v + EPS_);
    scl[c] = sc;
    shf[c] = bb[c] - m * sc;
  }
  __syncthreads();
  int t = blockIdx.x * 256 + threadIdx.x;
  int bn = t >> 6, c = t & 63;
  float s = 0.f;
#pragma unroll
  for (int k = 0; k < K2_; ++k)
    s += fmaxf(fmaf(bf2f(y3[(size_t)(bn * K2_ + k) * C_ + c]), scl[c], shf[c]), 0.f);
  fe[t] = s;
}

// ---------------- pooled[b][c] = sum_{n,k} relu(bn(y5)) ------------------------
__global__ __launch_bounds__(256) void k_pooled(const unsigned short* __restrict__ y5,
                                                const float* __restrict__ stat,
                                                const float* __restrict__ g,
                                                const float* __restrict__ bb,
                                                float* __restrict__ pooled) {
  __shared__ float scl[C_], shf[C_];
  __shared__ float red[4][C_];
  if (threadIdx.x < C_) {
    int c = threadIdx.x;
    float s = 0.f, s2 = 0.f;
#pragma unroll
    for (int u = 0; u < 8; ++u) {
      s += stat[c * 8 + u];
      s2 += stat[C_ * 8 + c * 8 + u];
    }
    const float invM = 1.f / (float)(BN_ * K1_);
    float m = s * invM;
    float v = s2 * invM - m * m;
    float sc = g[c] * rsqrtf(v + EPS_);
    scl[c] = sc;
    shf[c] = bb[c] - m * sc;
  }
  __syncthreads();
  int c = threadIdx.x & 63;
  int rs = threadIdx.x >> 6;
  int row0 = blockIdx.x * 64;
  int b = row0 / (N_ * K1_);
  float s = 0.f;
  for (int i = 0; i < 16; ++i) {
    int row = row0 + rs * 16 + i;
    s += fmaxf(fmaf(bf2f(y5[(size_t)row * C_ + c]), scl[c], shf[c]), 0.f);
  }
  red[rs][c] = s;
  __syncthreads();
  if (threadIdx.x < C_) {
    float t2 = red[0][c] + red[1][c] + red[2][c] + red[3][c];
    atomicAdd(&pooled[(b * C_ + c) * 8 + (blockIdx.x & 7)], t2);
  }
}

// ---------------- head ---------------------------------------------------------
__global__ void k_final(const float* __restrict__ pooled, const float* __restrict__ wq,
                        const float* __restrict__ bq, const float* __restrict__ wt,
                        const float* __restrict__ bt, const float* __restrict__ qc,
                        const float* __restrict__ tc, float* __restrict__ out) {
  int b = threadIdx.x;
  if (b >= B_) return;
  float P[C_];
#pragma unroll
  for (int c = 0; c < C_; ++c) {
    float s = 0.f;
#pragma unroll
    for (int u = 0; u < 8; ++u) s += pooled[(b * C_ + c) * 8 + u];
    P[c] = s;
  }
  float qd[4];
#pragma unroll
  for (int i = 0; i < 4; ++i) {
    float s = bq[i];
#pragma unroll
    for (int c = 0; c < C_; ++c) s = fmaf(P[c], wq[i * C_ + c], s);
    qd[i] = s;
  }
  float td[3];
#pragma unroll
  for (int i = 0; i < 3; ++i) {
    float s = bt[i];
#pragma unroll
    for (int c = 0; c < C_; ++c) s = fmaf(P[c], wt[i * C_ + c], s);
    td[i] = s;
  }
  float nq = sqrtf(qd[0] * qd[0] + qd[1] * qd[1] + qd[2] * qd[2] + qd[3] * qd[3]) + 1e-10f;
#pragma unroll
  for (int i = 0; i < 4; ++i) qd[i] /= nq;
  float cw = qc[b * 4 + 0], cx = qc[b * 4 + 1], cyy = qc[b * 4 + 2], cz = qc[b * 4 + 3];
  float qnw = qd[0] * cw - qd[1] * cx - qd[2] * cyy - qd[3] * cz;
  float qnx = qd[0] * cx + qd[1] * cw + qd[2] * cz - qd[3] * cyy;
  float qny = qd[0] * cyy - qd[1] * cz + qd[2] * cw + qd[3] * cx;
  float qnz = qd[0] * cz + qd[1] * cyy - qd[2] * cx + qd[3] * cw;
  float nn = sqrtf(qnw * qnw + qnx * qnx + qny * qny + qnz * qnz) + 1e-10f;
  float vx = tc[b * 3 + 0], vy = tc[b * 3 + 1], vz = tc[b * 3 + 2];
  float aw = -(qd[1] * vx + qd[2] * vy + qd[3] * vz);
  float ax = qd[0] * vx + qd[2] * vz - qd[3] * vy;
  float ay = qd[0] * vy - qd[1] * vz + qd[3] * vx;
  float az = qd[0] * vz + qd[1] * vy - qd[2] * vx;
  float n2 = qd[0] * qd[0] + qd[1] * qd[1] + qd[2] * qd[2] + qd[3] * qd[3] + 1e-10f;
  float bw = qd[0] / n2, bx = -qd[1] / n2, by = -qd[2] / n2, bz = -qd[3] / n2;
  float rx = aw * bx + ax * bw + ay * bz - az * by;
  float ry = aw * by - ax * bz + ay * bw + az * bx;
  float rz = aw * bz + ax * by - ay * bx + az * bw;
  out[b * 7 + 0] = qnw / nn;
  out[b * 7 + 1] = qnx / nn;
  out[b * 7 + 2] = qny / nn;
  out[b * 7 + 3] = qnz / nn;
  out[b * 7 + 4] = rx + td[0];
  out[b * 7 + 5] = ry + td[1];
  out[b * 7 + 6] = rz + td[2];
}

extern "C" void kernel_launch(void* const* d_in, const int* in_sizes, int n_in,
                              void* d_out, int out_size, void* d_ws, size_t ws_size,
                              hipStream_t stream) {
  const float* pos1 = (const float*)d_in[0];
  const float* pos2 = (const float*)d_in[1];
  const float* feat1 = (const float*)d_in[2];
  const float* feat2 = (const float*)d_in[3];
  const float* qc = (const float*)d_in[4];
  const float* tc = (const float*)d_in[5];
  const float* w1_0 = (const float*)d_in[6];
  const float* g1_0 = (const float*)d_in[7];
  const float* b1_0 = (const float*)d_in[8];
  const float* w1_1 = (const float*)d_in[9];
  const float* g1_1 = (const float*)d_in[10];
  const float* b1_1 = (const float*)d_in[11];
  const float* w1_2 = (const float*)d_in[12];
  const float* g1_2 = (const float*)d_in[13];
  const float* b1_2 = (const float*)d_in[14];
  const float* w2_0 = (const float*)d_in[15];
  const float* g2_0 = (const float*)d_in[16];
  const float* b2_0 = (const float*)d_in[17];
  const float* w2_1 = (const float*)d_in[18];
  const float* g2_1 = (const float*)d_in[19];
  const float* b2_1 = (const float*)d_in[20];
  const float* wq = (const float*)d_in[21];
  const float* bq = (const float*)d_in[22];
  const float* wt = (const float*)d_in[23];
  const float* bt = (const float*)d_in[24];

  float* ws = (float*)d_ws;
  const size_t off_posw = 0;                  // 49152
  const size_t off_fe = 49152;                // 1048576 (fp32)
  const size_t off_stat = 1097728;            // 8192
  const size_t off_pool = 1105920;            // 2048
  const size_t off_idx2 = 1107968;            // 98304 (int)
  const size_t off_idx1 = 1206272;            // 65536 (int)
  const size_t off_wb = 1271808;              // 30720 floats
  const size_t off_pts4w = 1302528;           // 65536
  const size_t off_pairW = 1368064;           // 65536
  const size_t off_pairP = 1433600;           // 65536
  const size_t off_partial = 1499136;         // 393216 (1536 blocks x 256)
  const size_t off_yA = 1892352;              // 6291456 floats = 12582912 bf16
  const size_t off_yB = 8183808;              // 3145728 floats = 6291456 bf16

  float* posw = ws + off_posw;
  float* fe = ws + off_fe;
  float* stat0 = ws + off_stat;  // 128*16
  float* stat1 = stat0 + 2048;   // 64*16
  float* stat2 = stat1 + 1024;   // 64*16
  float* stat3 = stat2 + 1024;   // 128*16
  float* stat4 = stat3 + 2048;   // 64*16
  float* pooled = ws + off_pool;
  int* idx2 = (int*)(ws + off_idx2);
  int* idx1 = (int*)(ws + off_idx1);
  unsigned short* wb0 = (unsigned short*)(ws + off_wb);  // 128x160
  unsigned short* wb1 = wb0 + 20480;                     // 64x128
  unsigned short* wb2 = wb1 + 8192;                      // 64x64
  unsigned short* wb3 = wb2 + 4096;                      // 128x160
  unsigned short* wb4 = wb3 + 20480;                     // 64x128
  float4* pts4w = (float4*)(ws + off_pts4w);
  float4* pairW = (float4*)(ws + off_pairW);
  float4* pairP = (float4*)(ws + off_pairP);
  float* partial = ws + off_partial;  // reused serially by all layers
  unsigned short* yA = (unsigned short*)(ws + off_yA);
  unsigned short* yB = (unsigned short*)(ws + off_yB);
  // KNN partial-key scratch overlaps yA (used strictly before the layer kernels)
  int* knnK = (int*)yA;

  // pooled still uses atomics -> zero it (ws is poisoned before every launch)
  hipMemsetAsync(ws + off_pool, 0, 2048 * sizeof(float), stream);

  k_wconv_all<<<dim3(80, 5), 256, 0, stream>>>(w1_0, w1_1, w1_2, w2_0, w2_1, wb0, wb1,
                                               wb2, wb3, wb4);
  k_pose<<<dim3(BN_ / 256), 256, 0, stream>>>(pos1, pos2, qc, tc, posw, pts4w, pairW,
                                              pairP);

  k_knn2<<<dim3(N_ / 256, NCH_, 2 * B_), 256, 0, stream>>>(pts4w, pairW, pairP, knnK);
  k_knn2_merge<<<dim3(2 * BN_ / 64), 64, 0, stream>>>(knnK, idx2, idx1);

  // MLP1 L0: gather -> 128ch
  k_layer_mfma<131, 128, 160, MODE_GATHER, K2_><<<dim3(1536), 256, 0, stream>>>(
      wb0, pos2, posw, feat2, feat1, idx2, nullptr, nullptr, nullptr, nullptr, 0.f, yA,
      partial);
  k_statreduce<128><<<dim3(8), 256, 0, stream>>>(partial, 1536, stat0);
  // MLP1 L1: 128->64
  k_layer_mfma<128, 64, 128, MODE_PLAIN, 1><<<dim3(1536), 256, 0, stream>>>(
      wb1, nullptr, nullptr, nullptr, nullptr, nullptr, yA, stat0, g1_0, b1_0,
      1.f / 98304.f, yB, partial);
  k_statreduce<64><<<dim3(8), 256, 0, stream>>>(partial, 1536, stat1);
  // MLP1 L2: 64->64
  k_layer_mfma<64, 64, 64, MODE_PLAIN, 1><<<dim3(1536), 256, 0, stream>>>(
      wb2, nullptr, nullptr, nullptr, nullptr, nullptr, yB, stat1, g1_1, b1_1,
      1.f / 98304.f, yA, partial);
  k_statreduce<64><<<dim3(8), 256, 0, stream>>>(partial, 1536, stat2);
  // fe = sum_k relu(bn(yA))
  k_fe<<<dim3(BN_ * C_ / 256), 256, 0, stream>>>(yA, stat2, g1_2, b1_2, fe);
  // MLP2 L0: gather -> 128ch
  k_layer_mfma<131, 128, 160, MODE_GATHER, K1_><<<dim3(1024), 256, 0, stream>>>(
      wb3, posw, posw, fe, feat1, idx1, nullptr, nullptr, nullptr, nullptr, 0.f, yA,
      partial);
  k_statreduce<128><<<dim3(8), 256, 0, stream>>>(partial, 1024, stat3);
  // MLP2 L1: 128->64
  k_layer_mfma<128, 64, 128, MODE_PLAIN, 1><<<dim3(1024), 256, 0, stream>>>(
      wb4, nullptr, nullptr, nullptr, nullptr, nullptr, yA, stat3, g2_0, b2_0,
      1.f / 65536.f, yB, partial);
  k_statreduce<64><<<dim3(8), 256, 0, stream>>>(partial, 1024, stat4);
  // pooled
  k_pooled<<<dim3(65536 / 64), 256, 0, stream>>>(yB, stat4, g2_1, b2_1, pooled);
  // head
  k_final<<<dim3(1), 64, 0, stream>>>(pooled, wq, bq, wt, bt, qc, tc, (float*)d_out);
}

// Round 9
// 386.812 us; speedup vs baseline: 2.3959x; 1.2620x over previous
//
#include <hip/hip_runtime.h>
#include <math.h>

#define B_ 4
#define N_ 4096
#define C_ 64
#define K1_ 4
#define K2_ 6
#define EPS_ 1e-5f
#define BN_ (B_ * N_)
#define NCH_ 16
#define CHP_ 256
#define STKD_ 16

typedef __attribute__((ext_vector_type(8))) short bf16x8;
typedef __attribute__((ext_vector_type(4))) float f32x4;
typedef __attribute__((ext_vector_type(2))) float f32x2;

__device__ __forceinline__ unsigned short f2bf(float f) {
  unsigned int u = __float_as_uint(f);
  unsigned int r = (u + 0x7fffu + ((u >> 16) & 1u)) >> 16;
  return (unsigned short)r;
}
__device__ __forceinline__ float bf2f(unsigned short u) {
  return __uint_as_float(((unsigned int)u) << 16);
}

// ---------------- init: weight conversion (7 blobs) + pose/tables --------------
// blockIdx.y: 0..6 weight extract/convert, 7 = pose (pos1_w + KNN point tables)
__global__ __launch_bounds__(256) void k_init(
    const float* __restrict__ w1_0, const float* __restrict__ w1_1,
    const float* __restrict__ w1_2, const float* __restrict__ w2_0,
    const float* __restrict__ w2_1, unsigned short* __restrict__ Wf2a,
    unsigned short* __restrict__ Wf1a, unsigned short* __restrict__ Wfe,
    unsigned short* __restrict__ Wf1b, unsigned short* __restrict__ wb1,
    unsigned short* __restrict__ wb2, unsigned short* __restrict__ wb4,
    const float* __restrict__ pos1, const float* __restrict__ pos2,
    const float* __restrict__ qc, const float* __restrict__ tc,
    float* __restrict__ posw, float4* __restrict__ pts4w, float4* __restrict__ pairW,
    float4* __restrict__ pairP) {
  int t = blockIdx.x * 256 + threadIdx.x;
  int m = blockIdx.y;
  if (m < 7) {
    switch (m) {
      case 0:
        if (t < 8192) Wf2a[t] = f2bf(w1_0[(t >> 6) * 131 + 3 + (t & 63)]);
        break;
      case 1:
        if (t < 8192) Wf1a[t] = f2bf(w1_0[(t >> 6) * 131 + 67 + (t & 63)]);
        break;
      case 2:
        if (t < 8192) Wfe[t] = f2bf(w2_0[(t >> 6) * 131 + 3 + (t & 63)]);
        break;
      case 3:
        if (t < 8192) Wf1b[t] = f2bf(w2_0[(t >> 6) * 131 + 67 + (t & 63)]);
        break;
      case 4:
        if (t < 8192) wb1[t] = f2bf(w1_1[t]);
        break;
      case 5:
        if (t < 4096) wb2[t] = f2bf(w1_2[t]);
        break;
      default:
        if (t < 8192) wb4[t] = f2bf(w2_1[t]);
        break;
    }
    return;
  }
  // pose
  if (t >= BN_) return;
  int b = t / N_;
  float qw = qc[b * 4 + 0], qx = qc[b * 4 + 1], qy = qc[b * 4 + 2], qz = qc[b * 4 + 3];
  float vx = pos1[t * 3 + 0], vy = pos1[t * 3 + 1], vz = pos1[t * 3 + 2];
  float aw = -(qx * vx + qy * vy + qz * vz);
  float ax = qw * vx + qy * vz - qz * vy;
  float ay = qw * vy - qx * vz + qz * vx;
  float az = qw * vz + qx * vy - qy * vx;
  float n2 = qw * qw + qx * qx + qy * qy + qz * qz + 1e-10f;
  float bw = qw / n2, bx = -qx / n2, by = -qy / n2, bz = -qz / n2;
  float rx = aw * bx + ax * bw + ay * bz - az * by;
  float ry = aw * by - ax * bz + ay * bw + az * bx;
  float rz = aw * bz + ax * by - ay * bx + az * bw;
  rx += tc[b * 3 + 0];
  ry += tc[b * 3 + 1];
  rz += tc[b * 3 + 2];
  posw[t * 3 + 0] = rx;
  posw[t * 3 + 1] = ry;
  posw[t * 3 + 2] = rz;
  float rw2 = rx * rx + ry * ry + rz * rz;
  pts4w[t] = make_float4(rx, ry, rz, rw2);
  int p = t >> 1, h = t & 1;
  float* bwp = (float*)&pairW[(size_t)2 * p];
  bwp[0 + h] = rx; bwp[2 + h] = ry; bwp[4 + h] = rz; bwp[6 + h] = rw2;
  float px = pos2[t * 3 + 0], py = pos2[t * 3 + 1], pz = pos2[t * 3 + 2];
  float pw2 = px * px + py * py + pz * pz;
  float* bpp = (float*)&pairP[(size_t)2 * p];
  bpp[0 + h] = px; bpp[2 + h] = py; bpp[4 + h] = pz; bpp[6 + h] = pw2;
}

// ---------------- branchless bubble top-6 insert on packed int keys ------------
__device__ __forceinline__ void ins6i(int (&kd)[6], int k) {
  int x = k;
#pragma unroll
  for (int u = 0; u < 6; ++u) {
    int lo = min(kd[u], x);
    x = max(kd[u], x);
    kd[u] = lo;
  }
}

// ---------------- fused dual-KNN, packed keys + LDS candidate stacks -----------
__global__ __launch_bounds__(256) void k_knn2(const float4* __restrict__ pts4w,
                                              const float4* __restrict__ pairW,
                                              const float4* __restrict__ pairP,
                                              int* __restrict__ outK) {
  __shared__ int st[STKD_][256];
  int tid = threadIdx.x;
  int b = blockIdx.z & 3;
  int which = blockIdx.z >> 2;
  const f32x4* __restrict__ PT =
      (const f32x4*)((which ? pairW : pairP) + (size_t)b * N_ + blockIdx.y * CHP_);
  int base = blockIdx.y * CHP_;
  int n = blockIdx.x * 256 + tid;
  float4 qv = pts4w[(size_t)b * N_ + n];
  f32x2 qq2 = (f32x2)(qv.w);
  f32x2 m2x = (f32x2)(-2.f * qv.x);
  f32x2 m2y = (f32x2)(-2.f * qv.y);
  f32x2 m2z = (f32x2)(-2.f * qv.z);
  int kd[6];
#pragma unroll
  for (int t = 0; t < 6; ++t) kd[t] = 0x7fffffff;
  int kbd5 = 0x7fffffff;
  int ptr = 0;
  for (int jj = 0; jj < CHP_; jj += 4) {
    f32x4 e0 = PT[jj + 0];
    f32x4 e1 = PT[jj + 1];
    f32x4 e2 = PT[jj + 2];
    f32x4 e3 = PT[jj + 3];
    f32x2 d01 = __builtin_elementwise_fma(
        m2x, e0.xy,
        __builtin_elementwise_fma(m2y, e0.zw,
                                  __builtin_elementwise_fma(m2z, e1.xy, e1.zw + qq2)));
    f32x2 d23 = __builtin_elementwise_fma(
        m2x, e2.xy,
        __builtin_elementwise_fma(m2y, e2.zw,
                                  __builtin_elementwise_fma(m2z, e3.xy, e3.zw + qq2)));
    int j0 = base + jj;
    int k0 = (int)((__float_as_uint(d01.x) & 0xFFFFF000u) | (unsigned)(j0 + 0));
    int k1 = (int)((__float_as_uint(d01.y) & 0xFFFFF000u) | (unsigned)(j0 + 1));
    int k2 = (int)((__float_as_uint(d23.x) & 0xFFFFF000u) | (unsigned)(j0 + 2));
    int k3 = (int)((__float_as_uint(d23.y) & 0xFFFFF000u) | (unsigned)(j0 + 3));
    st[ptr][tid] = k0;
    ptr += (k0 < kbd5) ? 1 : 0;
    st[ptr][tid] = k1;
    ptr += (k1 < kbd5) ? 1 : 0;
    st[ptr][tid] = k2;
    ptr += (k2 < kbd5) ? 1 : 0;
    st[ptr][tid] = k3;
    ptr += (k3 < kbd5) ? 1 : 0;
    if (__ballot(ptr >= STKD_ - 4)) {
      for (int i = 0; i < ptr; ++i) ins6i(kd, st[i][tid]);
      ptr = 0;
      kbd5 = kd[5];
    }
  }
  for (int i = 0; i < ptr; ++i) ins6i(kd, st[i][tid]);
  size_t ob =
      ((size_t)which * BN_ * NCH_ + (size_t)(b * N_ + n) * NCH_ + blockIdx.y) * 6;
#pragma unroll
  for (int t = 0; t < 6; ++t) outK[ob + t] = kd[t];
}

__global__ __launch_bounds__(64) void k_knn2_merge(const int* __restrict__ inK,
                                                   int* __restrict__ idx2,
                                                   int* __restrict__ idx1) {
  int t = blockIdx.x * 64 + threadIdx.x;
  if (t >= 2 * BN_) return;
  int which = (t >= BN_) ? 1 : 0;
  int qi = t - which * BN_;
  int kd[6];
#pragma unroll
  for (int u = 0; u < 6; ++u) kd[u] = 0x7fffffff;
  size_t ib = ((size_t)which * BN_ + qi) * NCH_ * 6;
  for (int c = 0; c < NCH_ * 6; ++c) ins6i(kd, inK[ib + c]);
  if (which) {
#pragma unroll
    for (int u = 0; u < K1_; ++u) idx1[(size_t)qi * K1_ + u] = kd[u] & 0xFFF;
  } else {
#pragma unroll
    for (int u = 0; u < K2_; ++u) idx2[(size_t)qi * K2_ + u] = kd[u] & 0xFFF;
  }
}

// ---------------- projection GEMM: P = src(16384x64 fp32) x Wb(128x64)^T -------
// blockIdx.y selects (src, W, dst) triple. Output fp32 [16384][128].
__global__ __launch_bounds__(256) void k_proj(
    const float* __restrict__ s0, const unsigned short* __restrict__ w0,
    float* __restrict__ d0, const float* __restrict__ s1,
    const unsigned short* __restrict__ w1, float* __restrict__ d1,
    const float* __restrict__ s2, const unsigned short* __restrict__ w2,
    float* __restrict__ d2) {
  const float* src;
  const unsigned short* Wb;
  float* dst;
  switch (blockIdx.y) {
    case 0: src = s0; Wb = w0; dst = d0; break;
    case 1: src = s1; Wb = w1; dst = d1; break;
    default: src = s2; Wb = w2; dst = d2; break;
  }
  constexpr int SP = 72;
  __shared__ unsigned short Xs[64 * SP];
  int tid = threadIdx.x;
  int row0 = blockIdx.x * 64;
  for (int e = tid; e < 64 * 16; e += 256) {
    int r = e >> 4, s = e & 15;
    float4 v = *(const float4*)&src[(size_t)(row0 + r) * 64 + s * 4];
    ushort4 o;
    o.x = f2bf(v.x); o.y = f2bf(v.y); o.z = f2bf(v.z); o.w = f2bf(v.w);
    *(ushort4*)&Xs[r * SP + s * 4] = o;
  }
  __syncthreads();
  int l = tid & 63, wv = tid >> 6;
  int lm = l & 15, quad = l >> 4;
  int n0 = wv * 32;
  f32x4 acc[4][2];
#pragma unroll
  for (int rt = 0; rt < 4; ++rt)
#pragma unroll
    for (int ct = 0; ct < 2; ++ct) acc[rt][ct] = (f32x4)(0.f);
#pragma unroll
  for (int k0 = 0; k0 < 64; k0 += 32) {
    bf16x8 a[4], b[2];
#pragma unroll
    for (int rt = 0; rt < 4; ++rt)
      a[rt] = *(const bf16x8*)&Xs[(rt * 16 + lm) * SP + k0 + quad * 8];
#pragma unroll
    for (int ct = 0; ct < 2; ++ct)
      b[ct] = *(const bf16x8*)&Wb[(size_t)(n0 + ct * 16 + lm) * 64 + k0 + quad * 8];
#pragma unroll
    for (int rt = 0; rt < 4; ++rt)
#pragma unroll
      for (int ct = 0; ct < 2; ++ct)
        acc[rt][ct] =
            __builtin_amdgcn_mfma_f32_16x16x32_bf16(a[rt], b[ct], acc[rt][ct], 0, 0, 0);
  }
#pragma unroll
  for (int rt = 0; rt < 4; ++rt)
#pragma unroll
    for (int ct = 0; ct < 2; ++ct)
#pragma unroll
      for (int r = 0; r < 4; ++r) {
        int row = row0 + rt * 16 + quad * 4 + r;
        dst[(size_t)row * 128 + n0 + ct * 16 + lm] = acc[rt][ct][r];
      }
}

// ---------------- assemble: y = P_j[gather] + P_n + xd*Wxd, BN stats -----------
// Block: 128 rows x 128 cols. Thread: cg=t&15 (8 cols), rg=t>>4 (8 rows).
template <int KNN>
__global__ __launch_bounds__(256) void k_asm(
    const float* __restrict__ Wfull,  // [128][131]; cols 0..2 = Wxd
    const float* __restrict__ posP, const float* __restrict__ posw,
    const float* __restrict__ Pj, const float* __restrict__ Pn,
    const int* __restrict__ idx, unsigned short* __restrict__ yout,
    float* __restrict__ statOut) {
  __shared__ float Wx[3][128];
  __shared__ float red[16][128];
  int tid = threadIdx.x;
  if (tid < 128) {
    Wx[0][tid] = Wfull[tid * 131 + 0];
    Wx[1][tid] = Wfull[tid * 131 + 1];
    Wx[2][tid] = Wfull[tid * 131 + 2];
  }
  __syncthreads();
  int cg = tid & 15, rg = tid >> 4;
  int c0 = cg * 8;
  int row0 = blockIdx.x * 128 + rg * 8;
  float wx0[8], wx1[8], wx2[8];
#pragma unroll
  for (int u = 0; u < 8; ++u) {
    wx0[u] = Wx[0][c0 + u];
    wx1[u] = Wx[1][c0 + u];
    wx2[u] = Wx[2][c0 + u];
  }
  float s1[8], s2[8];
#pragma unroll
  for (int u = 0; u < 8; ++u) { s1[u] = 0.f; s2[u] = 0.f; }
#pragma unroll
  for (int i = 0; i < 8; ++i) {
    int row = row0 + i;
    int g = row / KNN;           // b*N + n
    int bb = g >> 12;            // batch
    int j = idx[row];
    int gj = (bb << 12) + j;
    float xd0 = posP[(size_t)gj * 3 + 0] - posw[(size_t)g * 3 + 0];
    float xd1 = posP[(size_t)gj * 3 + 1] - posw[(size_t)g * 3 + 1];
    float xd2 = posP[(size_t)gj * 3 + 2] - posw[(size_t)g * 3 + 2];
    const float* pj = &Pj[(size_t)gj * 128 + c0];
    const float* pn = &Pn[(size_t)g * 128 + c0];
    float4 a0 = *(const float4*)&pj[0];
    float4 a1 = *(const float4*)&pj[4];
    float4 b0 = *(const float4*)&pn[0];
    float4 b1 = *(const float4*)&pn[4];
    float y[8];
    y[0] = a0.x + b0.x; y[1] = a0.y + b0.y; y[2] = a0.z + b0.z; y[3] = a0.w + b0.w;
    y[4] = a1.x + b1.x; y[5] = a1.y + b1.y; y[6] = a1.z + b1.z; y[7] = a1.w + b1.w;
    ushort4 o0, o1;
    unsigned short ob[8];
#pragma unroll
    for (int u = 0; u < 8; ++u) {
      float v = y[u];
      v = fmaf(xd0, wx0[u], v);
      v = fmaf(xd1, wx1[u], v);
      v = fmaf(xd2, wx2[u], v);
      s1[u] += v;
      s2[u] = fmaf(v, v, s2[u]);
      ob[u] = f2bf(v);
    }
    o0.x = ob[0]; o0.y = ob[1]; o0.z = ob[2]; o0.w = ob[3];
    o1.x = ob[4]; o1.y = ob[5]; o1.z = ob[6]; o1.w = ob[7];
    *(ushort4*)&yout[(size_t)row * 128 + c0] = o0;
    *(ushort4*)&yout[(size_t)row * 128 + c0 + 4] = o1;
  }
  int slot = blockIdx.x & 7;
  // reduce s1 across 16 rowgroups per column
#pragma unroll
  for (int u = 0; u < 8; ++u) red[rg][c0 + u] = s1[u];
  __syncthreads();
  if (tid < 128) {
    float s = 0.f;
#pragma unroll
    for (int r = 0; r < 16; ++r) s += red[r][tid];
    atomicAdd(&statOut[tid * 8 + slot], s);
  }
  __syncthreads();
#pragma unroll
  for (int u = 0; u < 8; ++u) red[rg][c0 + u] = s2[u];
  __syncthreads();
  if (tid < 128) {
    float s = 0.f;
#pragma unroll
    for (int r = 0; r < 16; ++r) s += red[r][tid];
    atomicAdd(&statOut[128 * 8 + tid * 8 + slot], s);
  }
}

// ---------------- BN-relu + bf16-MFMA GEMM layer (R6 structure, 8-slot atomics)-
template <int CIN, int COUT, int KP>
__global__ __launch_bounds__(256) void k_layer_mfma(
    const unsigned short* __restrict__ Wb,     // [COUT][KP] bf16
    const unsigned short* __restrict__ yprev,  // [rows][CIN] bf16
    const float* __restrict__ statPrev, const float* __restrict__ gPrev,
    const float* __restrict__ bPrev, float prevInvM,
    unsigned short* __restrict__ yout,  // [rows][COUT] bf16
    float* __restrict__ statOut) {
  constexpr int SP = KP + 8;
  constexpr int CST = COUT + 8;
  constexpr int CT = COUT / 64;
  __shared__ unsigned short Xs[64 * SP];
  __shared__ float scl[CIN];
  __shared__ float shf[CIN];

  int tid = threadIdx.x;
  int row0 = blockIdx.x * 64;

  for (int c = tid; c < CIN; c += 256) {
    float s = 0.f, s2 = 0.f;
#pragma unroll
    for (int u = 0; u < 8; ++u) {
      s += statPrev[c * 8 + u];
      s2 += statPrev[CIN * 8 + c * 8 + u];
    }
    float m = s * prevInvM;
    float v = s2 * prevInvM - m * m;
    float sc = gPrev[c] * rsqrtf(v + EPS_);
    scl[c] = sc;
    shf[c] = bPrev[c] - m * sc;
  }
  __syncthreads();
  constexpr int S4 = KP / 4;
  for (int e = tid; e < 64 * S4; e += 256) {
    int r = e / S4, s = e - r * S4;
    int row = row0 + r;
    ushort4 u = *(const ushort4*)&yprev[(size_t)row * CIN + s * 4];
    ushort4 o;
    o.x = f2bf(fmaxf(fmaf(bf2f(u.x), scl[s * 4 + 0], shf[s * 4 + 0]), 0.f));
    o.y = f2bf(fmaxf(fmaf(bf2f(u.y), scl[s * 4 + 1], shf[s * 4 + 1]), 0.f));
    o.z = f2bf(fmaxf(fmaf(bf2f(u.z), scl[s * 4 + 2], shf[s * 4 + 2]), 0.f));
    o.w = f2bf(fmaxf(fmaf(bf2f(u.w), scl[s * 4 + 3], shf[s * 4 + 3]), 0.f));
    *(ushort4*)&Xs[r * SP + s * 4] = o;
  }
  __syncthreads();

  int l = tid & 63, wv = tid >> 6;
  int lm = l & 15, quad = l >> 4;
  int n0 = wv * (COUT / 4);

  f32x4 acc[4][CT];
#pragma unroll
  for (int rt = 0; rt < 4; ++rt)
#pragma unroll
    for (int ct = 0; ct < CT; ++ct) acc[rt][ct] = (f32x4)(0.f);

#pragma unroll
  for (int k0 = 0; k0 < KP; k0 += 32) {
    bf16x8 a[4], b[CT];
#pragma unroll
    for (int rt = 0; rt < 4; ++rt)
      a[rt] = *(const bf16x8*)&Xs[(rt * 16 + lm) * SP + k0 + quad * 8];
#pragma unroll
    for (int ct = 0; ct < CT; ++ct)
      b[ct] = *(const bf16x8*)&Wb[(size_t)(n0 + ct * 16 + lm) * KP + k0 + quad * 8];
#pragma unroll
    for (int rt = 0; rt < 4; ++rt)
#pragma unroll
      for (int ct = 0; ct < CT; ++ct)
        acc[rt][ct] =
            __builtin_amdgcn_mfma_f32_16x16x32_bf16(a[rt], b[ct], acc[rt][ct], 0, 0, 0);
  }

  int slot = blockIdx.x & 7;
#pragma unroll
  for (int ct = 0; ct < CT; ++ct) {
    float s1 = 0.f, s2 = 0.f;
#pragma unroll
    for (int rt = 0; rt < 4; ++rt)
#pragma unroll
      for (int r = 0; r < 4; ++r) {
        float v = acc[rt][ct][r];
        s1 += v;
        s2 += v * v;
      }
    s1 += __shfl_xor(s1, 16);
    s1 += __shfl_xor(s1, 32);
    s2 += __shfl_xor(s2, 16);
    s2 += __shfl_xor(s2, 32);
    if (quad == 0) {
      int col = n0 + ct * 16 + lm;
      atomicAdd(&statOut[col * 8 + slot], s1);
      atomicAdd(&statOut[COUT * 8 + col * 8 + slot], s2);
    }
  }

  __syncthreads();
  unsigned short* Ys = Xs;
#pragma unroll
  for (int rt = 0; rt < 4; ++rt)
#pragma unroll
    for (int ct = 0; ct < CT; ++ct)
#pragma unroll
      for (int r = 0; r < 4; ++r)
        Ys[(rt * 16 + quad * 4 + r) * CST + n0 + ct * 16 + lm] = f2bf(acc[rt][ct][r]);
  __syncthreads();
  constexpr int S8 = COUT / 8;
  for (int e = tid; e < 64 * S8; e += 256) {
    int r = e / S8, c0 = (e - r * S8) * 8;
    uint4 v = *(const uint4*)&Ys[r * CST + c0];
    *(uint4*)&yout[((size_t)(row0 + r)) * COUT + c0] = v;
  }
}

// ---------------- fe = sum_k relu(bn(y3)), fp32 out ----------------------------
__global__ __launch_bounds__(256) void k_fe(const unsigned short* __restrict__ y3,
                                            const float* __restrict__ stat,
                                            const float* __restrict__ g,
                                            const float* __restrict__ bb,
                                            float* __restrict__ fe) {
  __shared__ float scl[C_], shf[C_];
  if (threadIdx.x < C_) {
    int c = threadIdx.x;
    float s = 0.f, s2 = 0.f;
#pragma unroll
    for (int u = 0; u < 8; ++u) {
      s += stat[c * 8 + u];
      s2 += stat[C_ * 8 + c * 8 + u];
    }
    const float invM = 1.f / (float)(BN_ * K2_);
    float m = s * invM;
    float v = s2 * invM - m * m;
    float sc = g[c] * rsqrtf(v + EPS_);
    scl[c] = sc;
    shf[c] = bb[c] - m * sc;
  }
  __syncthreads();
  int t = blockIdx.x * 256 + threadIdx.x;
  int bn = t >> 6, c = t & 63;
  float s = 0.f;
#pragma unroll
  for (int k = 0; k < K2_; ++k)
    s += fmaxf(fmaf(bf2f(y3[(size_t)(bn * K2_ + k) * C_ + c]), scl[c], shf[c]), 0.f);
  fe[t] = s;
}

// ---------------- pooled[b][c] = sum_{n,k} relu(bn(y5)) ------------------------
__global__ __launch_bounds__(256) void k_pooled(const unsigned short* __restrict__ y5,
                                                const float* __restrict__ stat,
                                                const float* __restrict__ g,
                                                const float* __restrict__ bb,
                                                float* __restrict__ pooled) {
  __shared__ float scl[C_], shf[C_];
  __shared__ float red[4][C_];
  if (threadIdx.x < C_) {
    int c = threadIdx.x;
    float s = 0.f, s2 = 0.f;
#pragma unroll
    for (int u = 0; u < 8; ++u) {
      s += stat[c * 8 + u];
      s2 += stat[C_ * 8 + c * 8 + u];
    }
    const float invM = 1.f / (float)(BN_ * K1_);
    float m = s * invM;
    float v = s2 * invM - m * m;
    float sc = g[c] * rsqrtf(v + EPS_);
    scl[c] = sc;
    shf[c] = bb[c] - m * sc;
  }
  __syncthreads();
  int c = threadIdx.x & 63;
  int rs = threadIdx.x >> 6;
  int row0 = blockIdx.x * 64;
  int b = row0 / (N_ * K1_);
  float s = 0.f;
  for (int i = 0; i < 16; ++i) {
    int row = row0 + rs * 16 + i;
    s += fmaxf(fmaf(bf2f(y5[(size_t)row * C_ + c]), scl[c], shf[c]), 0.f);
  }
  red[rs][c] = s;
  __syncthreads();
  if (threadIdx.x < C_) {
    float t2 = red[0][c] + red[1][c] + red[2][c] + red[3][c];
    atomicAdd(&pooled[(b * C_ + c) * 8 + (blockIdx.x & 7)], t2);
  }
}

// ---------------- head ---------------------------------------------------------
__global__ void k_final(const float* __restrict__ pooled, const float* __restrict__ wq,
                        const float* __restrict__ bq, const float* __restrict__ wt,
                        const float* __restrict__ bt, const float* __restrict__ qc,
                        const float* __restrict__ tc, float* __restrict__ out) {
  int b = threadIdx.x;
  if (b >= B_) return;
  float P[C_];
#pragma unroll
  for (int c = 0; c < C_; ++c) {
    float s = 0.f;
#pragma unroll
    for (int u = 0; u < 8; ++u) s += pooled[(b * C_ + c) * 8 + u];
    P[c] = s;
  }
  float qd[4];
#pragma unroll
  for (int i = 0; i < 4; ++i) {
    float s = bq[i];
#pragma unroll
    for (int c = 0; c < C_; ++c) s = fmaf(P[c], wq[i * C_ + c], s);
    qd[i] = s;
  }
  float td[3];
#pragma unroll
  for (int i = 0; i < 3; ++i) {
    float s = bt[i];
#pragma unroll
    for (int c = 0; c < C_; ++c) s = fmaf(P[c], wt[i * C_ + c], s);
    td[i] = s;
  }
  float nq = sqrtf(qd[0] * qd[0] + qd[1] * qd[1] + qd[2] * qd[2] + qd[3] * qd[3]) + 1e-10f;
#pragma unroll
  for (int i = 0; i < 4; ++i) qd[i] /= nq;
  float cw = qc[b * 4 + 0], cx = qc[b * 4 + 1], cyy = qc[b * 4 + 2], cz = qc[b * 4 + 3];
  float qnw = qd[0] * cw - qd[1] * cx - qd[2] * cyy - qd[3] * cz;
  float qnx = qd[0] * cx + qd[1] * cw + qd[2] * cz - qd[3] * cyy;
  float qny = qd[0] * cyy - qd[1] * cz + qd[2] * cw + qd[3] * cx;
  float qnz = qd[0] * cz + qd[1] * cyy - qd[2] * cx + qd[3] * cw;
  float nn = sqrtf(qnw * qnw + qnx * qnx + qny * qny + qnz * qnz) + 1e-10f;
  float vx = tc[b * 3 + 0], vy = tc[b * 3 + 1], vz = tc[b * 3 + 2];
  float aw = -(qd[1] * vx + qd[2] * vy + qd[3] * vz);
  float ax = qd[0] * vx + qd[2] * vz - qd[3] * vy;
  float ay = qd[0] * vy - qd[1] * vz + qd[3] * vx;
  float az = qd[0] * vz + qd[1] * vy - qd[2] * vx;
  float n2 = qd[0] * qd[0] + qd[1] * qd[1] + qd[2] * qd[2] + qd[3] * qd[3] + 1e-10f;
  float bw = qd[0] / n2, bx = -qd[1] / n2, by = -qd[2] / n2, bz = -qd[3] / n2;
  float rx = aw * bx + ax * bw + ay * bz - az * by;
  float ry = aw * by - ax * bz + ay * bw + az * bx;
  float rz = aw * bz + ax * by - ay * bx + az * bw;
  out[b * 7 + 0] = qnw / nn;
  out[b * 7 + 1] = qnx / nn;
  out[b * 7 + 2] = qny / nn;
  out[b * 7 + 3] = qnz / nn;
  out[b * 7 + 4] = rx + td[0];
  out[b * 7 + 5] = ry + td[1];
  out[b * 7 + 6] = rz + td[2];
}

extern "C" void kernel_launch(void* const* d_in, const int* in_sizes, int n_in,
                              void* d_out, int out_size, void* d_ws, size_t ws_size,
                              hipStream_t stream) {
  const float* pos1 = (const float*)d_in[0];
  const float* pos2 = (const float*)d_in[1];
  const float* feat1 = (const float*)d_in[2];
  const float* feat2 = (const float*)d_in[3];
  const float* qc = (const float*)d_in[4];
  const float* tc = (const float*)d_in[5];
  const float* w1_0 = (const float*)d_in[6];
  const float* g1_0 = (const float*)d_in[7];
  const float* b1_0 = (const float*)d_in[8];
  const float* w1_1 = (const float*)d_in[9];
  const float* g1_1 = (const float*)d_in[10];
  const float* b1_1 = (const float*)d_in[11];
  const float* w1_2 = (const float*)d_in[12];
  const float* g1_2 = (const float*)d_in[13];
  const float* b1_2 = (const float*)d_in[14];
  const float* w2_0 = (const float*)d_in[15];
  const float* g2_0 = (const float*)d_in[16];
  const float* b2_0 = (const float*)d_in[17];
  const float* w2_1 = (const float*)d_in[18];
  const float* g2_1 = (const float*)d_in[19];
  const float* b2_1 = (const float*)d_in[20];
  const float* wq = (const float*)d_in[21];
  const float* bq = (const float*)d_in[22];
  const float* wt = (const float*)d_in[23];
  const float* bt = (const float*)d_in[24];

  float* ws = (float*)d_ws;
  const size_t off_posw = 0;            // 49152
  const size_t off_fe = 49152;          // 1048576
  const size_t off_stat = 1097728;      // 8192
  const size_t off_pool = 1105920;      // 2048
  const size_t off_idx2 = 1107968;      // 98304 ints
  const size_t off_idx1 = 1206272;      // 65536 ints
  const size_t off_wb = 1271808;        // 52864 shorts -> 26624 floats
  const size_t off_pts4w = 1298432;     // 65536
  const size_t off_pairW = 1363968;     // 65536
  const size_t off_pairP = 1429504;     // 65536
  const size_t off_P2a = 1495040;       // 2097152
  const size_t off_P1a = 3592192;       // 2097152
  const size_t off_P1b = 5689344;       // 2097152
  const size_t off_Pfe = 7786496;       // 2097152
  const size_t off_yA = 9883648;        // 12582912 bf16 = 6291456 floats
  const size_t off_yB = 16175104;       // 6291456 bf16 = 3145728 floats

  float* posw = ws + off_posw;
  float* fe = ws + off_fe;
  float* stat0 = ws + off_stat;  // 128*16
  float* stat1 = stat0 + 2048;   // 64*16
  float* stat2 = stat1 + 1024;   // 64*16
  float* stat3 = stat2 + 1024;   // 128*16
  float* stat4 = stat3 + 2048;   // 64*16
  float* pooled = ws + off_pool;
  int* idx2 = (int*)(ws + off_idx2);
  int* idx1 = (int*)(ws + off_idx1);
  unsigned short* Wf2a = (unsigned short*)(ws + off_wb);  // 128x64
  unsigned short* Wf1a = Wf2a + 8192;                     // 128x64
  unsigned short* Wfe = Wf1a + 8192;                      // 128x64
  unsigned short* Wf1b = Wfe + 8192;                      // 128x64
  unsigned short* wb1 = Wf1b + 8192;                      // 64x128
  unsigned short* wb2 = wb1 + 8192;                       // 64x64
  unsigned short* wb4 = wb2 + 4096;                       // 64x128
  float4* pts4w = (float4*)(ws + off_pts4w);
  float4* pairW = (float4*)(ws + off_pairW);
  float4* pairP = (float4*)(ws + off_pairP);
  float* P2a = ws + off_P2a;
  float* P1a = ws + off_P1a;
  float* P1b = ws + off_P1b;
  float* Pfe = ws + off_Pfe;
  unsigned short* yA = (unsigned short*)(ws + off_yA);
  unsigned short* yB = (unsigned short*)(ws + off_yB);
  int* knnK = (int*)yA;  // KNN scratch, dead before layers

  // zero stats (atomic accumulators) + pooled
  hipMemsetAsync(ws + off_stat, 0, (8192 + 2048) * sizeof(float), stream);

  // init: 7 weight blobs + pose/tables
  k_init<<<dim3(64, 8), 256, 0, stream>>>(w1_0, w1_1, w1_2, w2_0, w2_1, Wf2a, Wf1a,
                                          Wfe, Wf1b, wb1, wb2, wb4, pos1, pos2, qc, tc,
                                          posw, pts4w, pairW, pairP);

  k_knn2<<<dim3(N_ / 256, NCH_, 2 * B_), 256, 0, stream>>>(pts4w, pairW, pairP, knnK);
  k_knn2_merge<<<dim3(2 * BN_ / 64), 64, 0, stream>>>(knnK, idx2, idx1);

  // projections: P2a = feat2*Wf2a^T, P1a = feat1*Wf1a^T, P1b = feat1*Wf1b^T
  k_proj<<<dim3(256, 3), 256, 0, stream>>>(feat2, Wf2a, P2a, feat1, Wf1a, P1a, feat1,
                                           Wf1b, P1b);
  // MLP1 L0 assemble: y = P2a[j] + P1a[n] + xd*Wxd -> yA (98304x128), stat0
  k_asm<K2_><<<dim3(98304 / 128), 256, 0, stream>>>(w1_0, pos2, posw, P2a, P1a, idx2,
                                                    yA, stat0);
  // MLP1 L1: 128->64
  k_layer_mfma<128, 64, 128><<<dim3(1536), 256, 0, stream>>>(
      wb1, yA, stat0, g1_0, b1_0, 1.f / 98304.f, yB, stat1);
  // MLP1 L2: 64->64
  k_layer_mfma<64, 64, 64><<<dim3(1536), 256, 0, stream>>>(
      wb2, yB, stat1, g1_1, b1_1, 1.f / 98304.f, yA, stat2);
  // fe
  k_fe<<<dim3(BN_ * C_ / 256), 256, 0, stream>>>(yA, stat2, g1_2, b1_2, fe);
  // Pfe = fe*Wfe^T
  k_proj<<<dim3(256, 1), 256, 0, stream>>>(fe, Wfe, Pfe, nullptr, nullptr, nullptr,
                                           nullptr, nullptr, nullptr);
  // MLP2 L0 assemble: y = Pfe[j] + P1b[n] + xd*W2xd -> yA (65536x128), stat3
  k_asm<K1_><<<dim3(65536 / 128), 256, 0, stream>>>(w2_0, posw, posw, Pfe, P1b, idx1,
                                                    yA, stat3);
  // MLP2 L1: 128->64
  k_layer_mfma<128, 64, 128><<<dim3(1024), 256, 0, stream>>>(
      wb4, yA, stat3, g2_0, b2_0, 1.f / 65536.f, yB, stat4);
  // pooled
  k_pooled<<<dim3(65536 / 64), 256, 0, stream>>>(yB, stat4, g2_1, b2_1, pooled);
  // head
  k_final<<<dim3(1), 64, 0, stream>>>(pooled, wq, bq, wt, bt, qc, tc, (float*)d_out);
}